// Round 1
// baseline (118.360 us; speedup 1.0000x reference)
//
#include <hip/hip_runtime.h>

#define THREADS 512

// -------- radix-8 inverse DFT over register index: u[n] = sum_k v[k] e^{+2*pi*i*n*k/8}
__device__ __forceinline__ void dft8(float* vr, float* vi) {
    float t0r=vr[0]+vr[4], t0i=vi[0]+vi[4];
    float t1r=vr[0]-vr[4], t1i=vi[0]-vi[4];
    float t2r=vr[2]+vr[6], t2i=vi[2]+vi[6];
    float t3r=vr[2]-vr[6], t3i=vi[2]-vi[6];
    float t4r=vr[1]+vr[5], t4i=vi[1]+vi[5];
    float t5r=vr[1]-vr[5], t5i=vi[1]-vi[5];
    float t6r=vr[3]+vr[7], t6i=vi[3]+vi[7];
    float t7r=vr[3]-vr[7], t7i=vi[3]-vi[7];
    float e0r=t0r+t2r, e0i=t0i+t2i;
    float e1r=t1r-t3i, e1i=t1i+t3r;   // t1 + i*t3
    float e2r=t0r-t2r, e2i=t0i-t2i;
    float e3r=t1r+t3i, e3i=t1i-t3r;   // t1 - i*t3
    float o0r=t4r+t6r, o0i=t4i+t6i;
    float o1r=t5r-t7i, o1i=t5i+t7r;
    float o2r=t4r-t6r, o2i=t4i-t6i;
    float o3r=t5r+t7i, o3i=t5i-t7r;
    const float C = 0.70710678118654752f;
    float w1r = C*(o1r - o1i), w1i = C*(o1r + o1i);   // W8^1 * o1
    float w2r = -o2i,          w2i = o2r;             // i * o2
    float w3r = -C*(o3r + o3i), w3i = C*(o3r - o3i);  // W8^3 * o3
    vr[0]=e0r+o0r; vi[0]=e0i+o0i;
    vr[1]=e1r+w1r; vi[1]=e1i+w1i;
    vr[2]=e2r+w2r; vi[2]=e2i+w2i;
    vr[3]=e3r+w3r; vi[3]=e3i+w3i;
    vr[4]=e0r-o0r; vi[4]=e0i-o0i;
    vr[5]=e1r-w1r; vi[5]=e1i-w1i;
    vr[6]=e2r-w2r; vi[6]=e2i-w2i;
    vr[7]=e3r-w3r; vi[7]=e3i-w3i;
}

// main: one block = (batch b, 32 frames). 512 threads = 8 waves.
// Each wave computes one 512-pt complex IFFT (packed irfft-1024) per round, 4 rounds.
__global__ __launch_bounds__(512, 4) void istft_main(const float* __restrict__ spec_re,
                                                     const float* __restrict__ spec_im,
                                                     const float* __restrict__ mask,
                                                     float* __restrict__ out)
{
    const int gg  = blockIdx.x;   // frame-group 0..63 (frames [32g, 32g+32))
    const int b   = blockIdx.y;   // batch 0..15
    const int tid = threadIdx.x;

    __shared__ float  s_slot[8320];   // 8 slots x 520: re at [slot*520+n], im at +4160
    __shared__ float  s_acc[8960];    // overlap-add accumulator, p_local in [0, 35*256)
    __shared__ float  s_wt[1024];     // hann(j)/512
    __shared__ float  s_w2[1024];     // hann(j)^2
    __shared__ float  s_mask[32];     // mask[b, 32g .. 32g+32)
    __shared__ float2 s_twzb[64];     // e^{i*pi*l/512}
    __shared__ float2 s_tw64[8];      // e^{2*pi*i*a/64}
    __shared__ float2 s_tw512[64];    // e^{2*pi*i*l/512}

    for (int i = tid; i < 1024; i += THREADS) {
        float w = 0.5f - 0.5f * cosf(6.2831853071795864f * (float)i * (1.0f/1024.0f));
        s_wt[i] = w * (1.0f/512.0f);
        s_w2[i] = w * w;
    }
    if (tid < 64) {
        float a1 = 3.1415926535897932f * (float)tid * (1.0f/512.0f);
        s_twzb[tid] = make_float2(cosf(a1), sinf(a1));
        float a2 = 6.2831853071795864f * (float)tid * (1.0f/512.0f);
        s_tw512[tid] = make_float2(cosf(a2), sinf(a2));
    }
    if (tid < 8) {
        float a = 6.2831853071795864f * (float)tid * (1.0f/64.0f);
        s_tw64[tid] = make_float2(cosf(a), sinf(a));
    }
    if (tid < 32) s_mask[tid] = mask[b*2048 + gg*32 + tid];
    for (int i = tid; i < 8960; i += THREADS) s_acc[i] = 0.0f;

    for (int r = 0; r < 4; ++r) {
        __syncthreads();   // prev gather done before slot overwrite
        // ---- stage spectra for 8 frames t = 32g + 8r + f (coalesced, read-once) ----
        const int t0 = gg*32 + r*8;
        const size_t rowbase = (size_t)b * 513 * 2048 + (size_t)t0;
        for (int i = tid; i < 2052; i += THREADS) {   // 513 rows x 4 float2
            int n = i >> 2, f2 = i & 3;
            size_t off = rowbase + (size_t)n * 2048 + (size_t)(f2*2);
            float2 vr = *(const float2*)(spec_re + off);
            float2 vi = *(const float2*)(spec_im + off);
            s_slot[       (f2*2+0)*520 + n] = vr.x;
            s_slot[       (f2*2+1)*520 + n] = vr.y;
            s_slot[4160 + (f2*2+0)*520 + n] = vi.x;
            s_slot[4160 + (f2*2+1)*520 + n] = vi.y;
        }
        __syncthreads();
        // ---- FFT: wave w handles frame f=w, in-place in slot w ----
        {
            const int w  = tid >> 6, l = tid & 63;
            const int a_ = l >> 3,  b_ = l & 7;
            float* Re = &s_slot[w*520];
            float* Im = &s_slot[4160 + w*520];
            float zr[8], zi[8];
            // Z build: Z[k] = E + i*e^{i*pi*k/512}*D, k = 64*k0 + l
            float cw = s_twzb[l].x, sw_ = s_twzb[l].y;
            const float C8 = 0.92387953251128675f, S8 = 0.38268343236508977f; // e^{i*pi/8}
            #pragma unroll
            for (int k0 = 0; k0 < 8; ++k0) {
                int k = (k0<<6) + l;
                float xkr = Re[k],     xki = Im[k];
                float xmr = Re[512-k], xmi = Im[512-k];
                if (k == 0) { xki = 0.f; xmi = 0.f; }   // zero Im(X0), Im(X512)
                float Er = 0.5f*(xkr + xmr), Ei = 0.5f*(xki - xmi);
                float Dr = 0.5f*(xkr - xmr), Di = 0.5f*(xki + xmi);
                float Or = cw*Dr - sw_*Di,  Oi = sw_*Dr + cw*Di;
                zr[k0] = Er - Oi;
                zi[k0] = Ei + Or;
                float nc = cw*C8 - sw_*S8; sw_ = sw_*C8 + cw*S8; cw = nc;
            }
            dft8(zr, zi);
            // exchange 1: write n0*64 + k1*8 + k2, read (l>>3)*64 + q*8 + (l&7); swizzled
            #pragma unroll
            for (int q = 0; q < 8; ++q) {
                int idx = (q<<6) + l;
                Re[idx ^ (((idx>>6)&7)<<3)] = zr[q];
                Im[idx ^ (((idx>>6)&7)<<3)] = zi[q];
            }
            #pragma unroll
            for (int q = 0; q < 8; ++q) {
                int idx = (a_<<6) + (q<<3) + b_;
                int ph = idx ^ (((idx>>6)&7)<<3);
                zr[q] = Re[ph]; zi[q] = Im[ph];
            }
            { // twiddle2: w64^{n0*k1}, incremental
                float c1 = s_tw64[a_].x, s1 = s_tw64[a_].y;
                float cr = c1, ci = s1;
                #pragma unroll
                for (int q = 1; q < 8; ++q) {
                    float tr = zr[q]*cr - zi[q]*ci;
                    zi[q] = zr[q]*ci + zi[q]*cr;
                    zr[q] = tr;
                    float nc = cr*c1 - ci*s1; ci = ci*c1 + cr*s1; cr = nc;
                }
            }
            dft8(zr, zi);
            // exchange 2: write k2*64 + n1*8 + n0, read q*64 + l; swizzled
            #pragma unroll
            for (int q = 0; q < 8; ++q) {
                int idx = (b_<<6) + (q<<3) + a_;
                int ph = idx ^ (((idx>>6)&7)<<3);
                Re[ph] = zr[q]; Im[ph] = zi[q];
            }
            #pragma unroll
            for (int q = 0; q < 8; ++q) {
                int idx = (q<<6) + l;
                int ph = idx ^ (((idx>>6)&7)<<3);
                zr[q] = Re[ph]; zi[q] = Im[ph];
            }
            { // twiddle3: w512^{(n1*8+n0)*k2}, incremental
                float c1 = s_tw512[l].x, s1 = s_tw512[l].y;
                float cr = c1, ci = s1;
                #pragma unroll
                for (int q = 1; q < 8; ++q) {
                    float tr = zr[q]*cr - zi[q]*ci;
                    zi[q] = zr[q]*ci + zi[q]*cr;
                    zr[q] = tr;
                    float nc = cr*c1 - ci*s1; ci = ci*c1 + cr*s1; cr = nc;
                }
            }
            dft8(zr, zi);
            // output: lane l, reg q holds z[64q + l]; x[2n]=Re z[n], x[2n+1]=Im z[n]
            #pragma unroll
            for (int q = 0; q < 8; ++q) {
                Re[(q<<6) + l] = zr[q];
                Im[(q<<6) + l] = zi[q];
            }
        }
        __syncthreads();
        // ---- gather: overlap-add this round's 8 frames into s_acc (race-free) ----
        const int base_p = r << 11;   // window [2048r, 2048r+2816)
        const int r8 = r << 3;
        for (int q = tid; q < 2816; q += THREADS) {
            int p = base_p + q;
            int Fhi = min(r8 + 7, p >> 8);
            int Flo = max(r8, (p - 768) >> 8);    // ceil((p-1023)/256)
            float acc = s_acc[p];
            for (int F = Flo; F <= Fhi; ++F) {
                int j = p - (F << 8);
                float v = s_slot[(j & 1)*4160 + (F - r8)*520 + (j >> 1)];
                acc += v * s_wt[j] * s_mask[F];
            }
            s_acc[p] = acc;
        }
    }
    __syncthreads();
    // ---- write phase ----
    const int P0 = gg << 13;                       // 8192*g
    float* yout = out + (size_t)b * 524288;
    float* mout = out + 16ull*524288 + (size_t)b * 524288;
    const int lo = (gg == 0)  ? 384  : 768;
    const int hi = (gg == 63) ? 8576 : 8192;
    for (int p = lo + tid; p < hi; p += THREADS) {
        int P = P0 + p;
        int thi = min(2047, P >> 8);
        int tlo = max(0, (P - 768) >> 8);
        float env = 0.f, fm = 0.f;
        for (int t = tlo; t <= thi; ++t) {
            int j = P - (t << 8);
            env += s_w2[j];
            fm  += s_mask[t - (gg << 5)];
        }
        int s = P - 384;
        yout[s] = s_acc[p] / env;
        mout[s] = (fm > 0.f) ? 1.f : 0.f;
    }
    // boundary strips: partial sums via atomics (zeroed before, env-divided after)
    if (gg > 0) {
        for (int p = tid; p < 768; p += THREADS)
            atomicAdd(&yout[P0 + p - 384], s_acc[p]);
    }
    if (gg < 63) {
        for (int p = 8192 + tid; p < 8960; p += THREADS)
            atomicAdd(&yout[P0 + p - 384], s_acc[p]);
    }
}

__global__ void istft_zero(float* __restrict__ out) {
    int idx = blockIdx.x * 256 + threadIdx.x;
    if (idx >= 16*63*768) return;
    int q  = idx % 768;
    int t_ = idx / 768;
    int G  = (t_ % 63) + 1;
    int b  = t_ / 63;
    out[(size_t)b*524288 + (G << 13) + q - 384] = 0.f;
}

__global__ void istft_fixup(const float* __restrict__ mask, float* __restrict__ out) {
    int idx = blockIdx.x * 256 + threadIdx.x;
    if (idx >= 16*63*768) return;
    int q  = idx % 768;
    int t_ = idx / 768;
    int G  = (t_ % 63) + 1;
    int b  = t_ / 63;
    int P  = (G << 13) + q;
    int thi = min(2047, P >> 8);
    int tlo = (P - 768) >> 8;
    float env = 0.f, fm = 0.f;
    for (int t = tlo; t <= thi; ++t) {
        int j = P - (t << 8);
        float w = 0.5f - 0.5f * __cosf(6.2831853071795864f * (float)j * (1.0f/1024.0f));
        env += w * w;
        fm  += mask[b*2048 + t];
    }
    size_t o = (size_t)b*524288 + (size_t)(P - 384);
    out[o] = out[o] / env;
    out[16ull*524288 + o] = (fm > 0.f) ? 1.f : 0.f;
}

extern "C" void kernel_launch(void* const* d_in, const int* in_sizes, int n_in,
                              void* d_out, int out_size, void* d_ws, size_t ws_size,
                              hipStream_t stream) {
    (void)in_sizes; (void)n_in; (void)d_ws; (void)ws_size; (void)out_size;
    const float* spec_re = (const float*)d_in[0];
    const float* spec_im = (const float*)d_in[1];
    const float* mask    = (const float*)d_in[2];
    float* out = (float*)d_out;
    const int nstrip = 16*63*768;
    istft_zero <<<(nstrip + 255)/256, 256, 0, stream>>>(out);
    istft_main <<<dim3(64, 16), 512, 0, stream>>>(spec_re, spec_im, mask, out);
    istft_fixup<<<(nstrip + 255)/256, 256, 0, stream>>>(mask, out);
}